// Round 1
// baseline (768.657 us; speedup 1.0000x reference)
//
#include <hip/hip_runtime.h>

typedef __attribute__((ext_vector_type(8))) short short8;
typedef __attribute__((ext_vector_type(4))) float floatx4;

constexpr int DIM = 128;   // dim_in == dim_out
constexpr int NB  = 4;     // bases
constexpr int NR  = 8;     // relations

static __device__ __forceinline__ unsigned short f2bf(float f) {
    // round-to-nearest-even fp32 -> bf16 (bit trick; inputs finite)
    unsigned int u = __float_as_uint(f);
    u += 0x7FFFu + ((u >> 16) & 1u);
    return (unsigned short)(u >> 16);
}

// ---------------------------------------------------------------------------
// K1: build W_r = sum_b A[r,b] * V[b] in bf16, pre-swizzled into MFMA
// B-operand fragment layout:
//   Wfrag[r][ot][ks][lane][j]  (j=0..7, 16B per lane)
//   value = W[r][k][o], k = ks*32 + (lane>>4)*8 + j, o = ot*16 + (lane&15)
// 8*8*4*64 = 16384 threads, each writes 16B.
// ---------------------------------------------------------------------------
__global__ __launch_bounds__(256) void build_wfrag(
    const float* __restrict__ A, const float* __restrict__ V,
    unsigned short* __restrict__ Wfrag)
{
    int idx  = blockIdx.x * 256 + threadIdx.x;   // 0 .. 16383
    int lane = idx & 63;
    int ks   = (idx >> 6) & 3;
    int ot   = (idx >> 8) & 7;
    int r    = idx >> 11;

    int o     = ot * 16 + (lane & 15);
    int kbase = ks * 32 + (lane >> 4) * 8;

    float a0 = A[r * NB + 0], a1 = A[r * NB + 1];
    float a2 = A[r * NB + 2], a3 = A[r * NB + 3];

    short8 v;
#pragma unroll
    for (int j = 0; j < 8; ++j) {
        int k = kbase + j;
        float w = a0 * V[(0 * DIM + k) * DIM + o]
                + a1 * V[(1 * DIM + k) * DIM + o]
                + a2 * V[(2 * DIM + k) * DIM + o]
                + a3 * V[(3 * DIM + k) * DIM + o];
        v[j] = (short)f2bf(w);
    }
    *reinterpret_cast<short8*>(Wfrag + (size_t)idx * 8) = v;
}

// ---------------------------------------------------------------------------
// K2: H (fp32) -> Hbf (bf16), row-major [Ne][128]
// ---------------------------------------------------------------------------
__global__ __launch_bounds__(256) void h_to_bf(
    const float* __restrict__ H, unsigned short* __restrict__ Hbf, int n8)
{
    int i = blockIdx.x * 256 + threadIdx.x;
    if (i >= n8) return;
    const float4* hp = reinterpret_cast<const float4*>(H) + (size_t)i * 2;
    float4 f0 = hp[0];
    float4 f1 = hp[1];
    short8 v;
    v[0] = (short)f2bf(f0.x); v[1] = (short)f2bf(f0.y);
    v[2] = (short)f2bf(f0.z); v[3] = (short)f2bf(f0.w);
    v[4] = (short)f2bf(f1.x); v[5] = (short)f2bf(f1.y);
    v[6] = (short)f2bf(f1.z); v[7] = (short)f2bf(f1.w);
    *reinterpret_cast<short8*>(Hbf + (size_t)i * 8) = v;
}

// ---------------------------------------------------------------------------
// K3: fused gather -> (16 edges x 128) @ W_r -> scale by val -> atomic scatter
// One wave processes groups of 16 edges of its fixed relation.
// A-frag:  A[m = lane&15][k = ks*32 + (lane>>4)*8 + j] = Hbf[col_m][k]
// B-frag:  preloaded registers (Wfrag layout above)
// C/D:     D[row = (lane>>4)*4 + reg][col = lane&15]
// ---------------------------------------------------------------------------
__global__ __launch_bounds__(256) void rgcn_main(
    const unsigned short* __restrict__ Hbf,
    const unsigned short* __restrict__ Wfrag,
    const int*   __restrict__ erow,
    const int*   __restrict__ ecol,
    const float* __restrict__ eval,
    float*       __restrict__ out,
    int E, int groups_per_rel, int waves_per_rel)
{
    int wid  = blockIdx.x * 4 + (threadIdx.x >> 6);
    int lane = threadIdx.x & 63;
    int r    = wid / waves_per_rel;
    int wr   = wid % waves_per_rel;
    int quad = lane >> 4;
    int l15  = lane & 15;

    // Load this relation's W fragments into registers (held for whole kernel)
    short8 b[8][4];
    {
        const short8* wp = reinterpret_cast<const short8*>(
            Wfrag + ((size_t)r * 8 * 4 * 64) * 8);
#pragma unroll
        for (int ot = 0; ot < 8; ++ot)
#pragma unroll
            for (int ks = 0; ks < 4; ++ks)
                b[ot][ks] = wp[(ot * 4 + ks) * 64 + lane];
    }

    for (int g = wr; g < groups_per_rel; g += waves_per_rel) {
        int ebase = r * E + g * 16;

        int   colv = ecol[ebase + l15];
        int   rowv = erow[ebase + l15];
        float valv = eval[ebase + l15];

        // gather A fragments: lane reads 4x16B from row colv
        short8 a[4];
        const unsigned short* hp = Hbf + (size_t)colv * DIM + quad * 8;
#pragma unroll
        for (int ks = 0; ks < 4; ++ks)
            a[ks] = *reinterpret_cast<const short8*>(hp + ks * 32);

        floatx4 acc[8];
#pragma unroll
        for (int ot = 0; ot < 8; ++ot) acc[ot] = (floatx4){0.f, 0.f, 0.f, 0.f};

#pragma unroll
        for (int ot = 0; ot < 8; ++ot)
#pragma unroll
            for (int ks = 0; ks < 4; ++ks)
                acc[ot] = __builtin_amdgcn_mfma_f32_16x16x32_bf16(
                    a[ks], b[ot][ks], acc[ot], 0, 0, 0);

        // rows / vals for the 4 D-rows this lane's quad owns
        int   row4[4];
        float val4[4];
#pragma unroll
        for (int reg = 0; reg < 4; ++reg) {
            int src  = quad * 4 + reg;
            row4[reg] = __shfl(rowv, src, 64);
            val4[reg] = __shfl(valv, src, 64);
        }

#pragma unroll
        for (int ot = 0; ot < 8; ++ot) {
#pragma unroll
            for (int reg = 0; reg < 4; ++reg) {
                float m = acc[ot][reg] * val4[reg];
                atomicAdd(out + (size_t)row4[reg] * DIM + ot * 16 + l15, m);
            }
        }
    }
}

extern "C" void kernel_launch(void* const* d_in, const int* in_sizes, int n_in,
                              void* d_out, int out_size, void* d_ws, size_t ws_size,
                              hipStream_t stream)
{
    const float* H    = (const float*)d_in[0];
    const float* A    = (const float*)d_in[1];
    const float* V    = (const float*)d_in[2];
    const int*   erow = (const int*)d_in[3];
    const int*   ecol = (const int*)d_in[4];
    const float* eval = (const float*)d_in[5];
    float* out = (float*)d_out;

    int Ne = in_sizes[0] / DIM;          // 100000
    int E  = in_sizes[3] / NR;           // 200000

    // workspace layout
    unsigned short* Hbf   = (unsigned short*)d_ws;                  // Ne*128 bf16
    unsigned short* Wfrag = Hbf + (size_t)Ne * DIM;                 // 16384*8 bf16

    // zero the output accumulator
    hipMemsetAsync(d_out, 0, (size_t)Ne * DIM * sizeof(float), stream);

    // K1: W fragments
    build_wfrag<<<64, 256, 0, stream>>>(A, V, Wfrag);

    // K2: H -> bf16
    int n8 = Ne * DIM / 8;
    h_to_bf<<<(n8 + 255) / 256, 256, 0, stream>>>(H, Hbf, n8);

    // K3: main fused kernel
    int blocks = 512;                       // 2048 waves, 256 per relation
    int waves_per_rel = blocks * 4 / NR;
    int groups_per_rel = E / 16;            // 12500
    rgcn_main<<<blocks, 256, 0, stream>>>(Hbf, Wfrag, erow, ecol, eval, out,
                                          E, groups_per_rel, waves_per_rel);
}